// Round 3
// baseline (143.797 us; speedup 1.0000x reference)
//
#include <hip/hip_runtime.h>

#define NB      2000
#define NT      365
#define NMUL    8
#define LENF    15
#define PSTRIDE 96              // 12 params * 8 muls, floats per (b,t)
#define CH      8               // timesteps per chunk
#define NFULL   45              // full chunks (360 steps)
#define NCHUNK  46              // incl. 5-step tail
#define BWORDS  772             // padded LDS words per basin-chunk (768 data + 4 pad); 772%32=4
#define BASIN_BYTES (NT * PSTRIDE * 4)          // 140160
#define CLAMP16     (BASIN_BYTES - 16)          // 140144
#define FCLAMP      (NT * 4 - 4)                // 1456

#define GLD16(g, l) __builtin_amdgcn_global_load_lds( \
    (const __attribute__((address_space(1))) void*)(g), \
    (__attribute__((address_space(3))) void*)(l), 16, 0, 0)
#define GLD4(g, l) __builtin_amdgcn_global_load_lds( \
    (const __attribute__((address_space(1))) void*)(g), \
    (__attribute__((address_space(3))) void*)(l), 4, 0, 0)

#define EXP2F(x) __builtin_amdgcn_exp2f(x)
#define LOG2F(x) __builtin_amdgcn_logf(x)
#define LOG2E    1.44269504088896f

// One thread per (basin, mul). Block = 64 threads = 1 wave = 8 basins.
// Params + forcings streamed global->LDS via global_load_lds, depth-2 chunk
// pipeline with counted vmcnt (never 0 in main loop). Q history in LDS,
// gamma routing conv fused (gammaln/th^aa denominator cancels under norm).
__global__ __launch_bounds__(64) void prms_kernel(
    const float* __restrict__ P, const float* __restrict__ Ep,
    const float* __restrict__ Tair, const float* __restrict__ params,
    const float* __restrict__ rout_a, const float* __restrict__ rout_b,
    float* __restrict__ out)
{
  __shared__ __attribute__((aligned(16))) float sh_par[2][8 * BWORDS]; // 49408 B
  __shared__ __attribute__((aligned(16))) float sh_frc[2][3][64];      //  1536 B
  __shared__ float Qs[8][NT];                                          // 11680 B

  const int lane = threadIdx.x;      // 0..63
  const int lb   = lane >> 3;        // local basin 0..7
  const int m    = lane & 7;         // mul index
  const int b0   = blockIdx.x * 8;   // first basin of this block (grid exact)
  const int b    = b0 + lb;

  // ---- staging: 24x GLD16 (params) + 3x GLD4 (forcings) per chunk ----
  auto ISSUE = [&](int c, int buf) {
    #pragma unroll
    for (int q = 0; q < 8; ++q) {
      const char* gb = (const char*)(params + (size_t)(b0 + q) * (NT * PSTRIDE));
      #pragma unroll
      for (int j = 0; j < 3; ++j) {
        int off = c * (CH * PSTRIDE * 4) + j * 1024 + lane * 16;
        off = off > CLAMP16 ? CLAMP16 : off;   // tail clamp (dup reads, unused)
        GLD16(gb + off, &sh_par[buf][q * BWORDS + j * 256]);
      }
    }
    const int fl = lane >> 3, fs = lane & 7;   // lane i -> (basin fl, step fs)
    int foff = c * (CH * 4) + fs * 4;
    foff = foff > FCLAMP ? FCLAMP : foff;
    GLD4((const char*)(P    + (size_t)(b0 + fl) * NT) + foff, &sh_frc[buf][0][0]);
    GLD4((const char*)(Ep   + (size_t)(b0 + fl) * NT) + foff, &sh_frc[buf][1][0]);
    GLD4((const char*)(Tair + (size_t)(b0 + fl) * NT) + foff, &sh_frc[buf][2][0]);
  };

  float S1 = 0.5f, S2 = 0.5f, S3 = 0.5f, S4 = 0.5f, S5 = 0.5f;
  const int pbase = lb * BWORDS + m;   // per-thread param word base
  const int fbase = lb * 8;

  auto STEP = [&](int buf, int s, int t) {
    const float* par = &sh_par[buf][pbase + s * PSTRIDE];
    const float v0  = par[0];    // pr0  -> tt
    const float v1  = par[8];    // pr1  -> ddf
    const float v3  = par[24];   // pr3  -> Smax3
    const float v4  = par[32];   // pr4  -> p_lo
    const float v5  = par[40];   // pr5  -> p_hi
    const float v6  = par[48];   // pr6  -> p_exp
    const float i1  = par[64];   // pr8
    const float i2  = par[72] * 0.001f;  // pr9
    const float kb  = par[80];   // pr10
    const float Pt  = sh_frc[buf][0][fbase + s];
    const float Ept = sh_frc[buf][1][fbase + s];
    const float Tt  = sh_frc[buf][2][fbase + s];

    const float tt    = fmaf(v0, 8.0f, -3.0f);
    const float ddf   = v1 * 20.0f;
    const float Smax3 = fmaf(v3, 680.0f, 20.0f);
    const float p_lo  = fmaf(v4, 0.99f, 0.005f);
    const float p_hi  = fmaf(v5, 0.99f, 0.005f);
    const float p_exp = fmaf(v6, 4.0f, 1.0f);

    const float snow = (Tt <= tt) ? Pt : 0.0f;
    const float rain = Pt - snow;
    const float melt = fmaxf(fminf(ddf * (Tt - tt), S1), 0.0f);   // DT=1
    S1 = S1 + snow - melt;

    const float inter = rain * 0.95f;
    const float evap2 = fminf(S2, Ept);
    S2 = fmaxf(S2 + (rain - inter) - evap2, 0.0f);

    const float infil  = melt + inter;
    const float frac   = fmaxf(S3, 0.0f) * __builtin_amdgcn_rcpf(Smax3);
    const float satexc = (p_lo + (p_hi - p_lo) * frac) * infil;
    const float rem    = fmaxf(infil - satexc, 0.0f);
    // frac^p_exp: frac==0 -> log2=-inf -> exp2(-inf)=0 (matches 0**p, p>=1)
    const float rech   = rem * EXP2F(p_exp * LOG2F(frac));
    const float evap3  = fminf(frac * Ept, S3);
    S3 = S3 + rem - rech - evap3;

    const float S4c   = fmaxf(S4, 0.0f);
    const float iflow = fminf(S4c, fmaf(i2, S4c * S4c, i1 * S4c));
    S4 = S4 + rech - iflow;

    const float base = kb * S5;
    S5 = S5 + iflow - base;

    float q = satexc + base;
    q += __shfl_xor(q, 1);
    q += __shfl_xor(q, 2);
    q += __shfl_xor(q, 4);
    if (m == 0) Qs[lb][t] = q * 0.125f;
  };

  // ---- depth-2 pipeline over 46 chunks ----
  ISSUE(0, 0);
  ISSUE(1, 1);
  for (int c = 0; c < NFULL; ++c) {
    asm volatile("s_waitcnt vmcnt(27)" ::: "memory");  // chunk c resident (c+1 in flight)
    const int buf = c & 1;
    #pragma unroll
    for (int s = 0; s < CH; ++s) STEP(buf, s, c * CH + s);
    asm volatile("s_waitcnt lgkmcnt(0)" ::: "memory"); // reads of buf drained
    if (c + 2 < NCHUNK) ISSUE(c + 2, buf);
  }
  // tail chunk (c = 45): 5 valid steps
  asm volatile("s_waitcnt vmcnt(0)" ::: "memory");
  #pragma unroll
  for (int s = 0; s < 5; ++s) STEP(NFULL & 1, s, NFULL * CH + s);

  __syncthreads();

  // ---- fused gamma routing conv ----
  const float aa  = fmaxf(rout_a[b] * 2.9f, 0.0f) + 0.1f;
  const float th  = fmaxf(rout_b[b] * 6.5f, 0.0f) + 0.5f;
  const float am1 = aa - 1.0f;
  const float ith = -LOG2E / th;

  float w[LENF];
  float wsum = 0.0f;
  #pragma unroll
  for (int j = 0; j < LENF; ++j) {
    const float tj = (float)j + 0.5f;
    w[j] = EXP2F(fmaf(am1, LOG2F(tj), tj * ith));
    wsum += w[j];
  }
  const float inv = 1.0f / wsum;
  #pragma unroll
  for (int j = 0; j < LENF; ++j) w[j] *= inv;

  float* __restrict__ ob = out + (size_t)b * NT;
  for (int t = m; t < NT; t += NMUL) {
    float acc = 0.0f;
    #pragma unroll
    for (int j = 0; j < LENF; ++j) {
      const int idx = t - j;
      if (idx >= 0) acc += w[j] * Qs[lb][idx];
    }
    ob[t] = acc;
  }
}

extern "C" void kernel_launch(void* const* d_in, const int* in_sizes, int n_in,
                              void* d_out, int out_size, void* d_ws, size_t ws_size,
                              hipStream_t stream) {
  const float* P      = (const float*)d_in[0];
  const float* Ep     = (const float*)d_in[1];
  const float* Tair   = (const float*)d_in[2];
  const float* params = (const float*)d_in[3];
  const float* ra     = (const float*)d_in[4];
  const float* rb     = (const float*)d_in[5];
  float* out = (float*)d_out;

  prms_kernel<<<(NB * NMUL) / 64, 64, 0, stream>>>(P, Ep, Tair, params, ra, rb, out);
}

// Round 4
// 126.690 us; speedup vs baseline: 1.1350x; 1.1350x over previous
//
#include <hip/hip_runtime.h>

#define NB      2000
#define NT      365
#define NMUL    8
#define LENF    15
#define PSTRIDE 96              // 12 params * 8 muls, floats per (b,t)
#define CH      8               // timesteps per chunk
#define NFULL   45              // full chunks (360 steps)
#define NCHUNK  46              // incl. 5-step tail
#define BWORDS  772             // padded LDS words per basin-chunk (768 data + 4 pad); 772%32=4
#define BASIN_BYTES (NT * PSTRIDE * 4)          // 140160
#define CLAMP16     (BASIN_BYTES - 16)          // 140144
#define FCLAMP      (NT * 4 - 4)                // 1456

#define GLD16(g, l) __builtin_amdgcn_global_load_lds( \
    (const __attribute__((address_space(1))) void*)(g), \
    (__attribute__((address_space(3))) void*)(l), 16, 0, 0)
#define GLD4(g, l) __builtin_amdgcn_global_load_lds( \
    (const __attribute__((address_space(1))) void*)(g), \
    (__attribute__((address_space(3))) void*)(l), 4, 0, 0)

#define EXP2F(x) __builtin_amdgcn_exp2f(x)
#define LOG2F(x) __builtin_amdgcn_logf(x)
#define LOG2E    1.44269504088896f

// DPP cross-lane xor within quads — pure VALU, no LDS latency, no lgkmcnt.
template <int CTRL>
__device__ __forceinline__ float dpp_xor(float x) {
  int xi = __float_as_int(x);
  int r  = __builtin_amdgcn_update_dpp(xi, xi, CTRL, 0xF, 0xF, true);
  return __int_as_float(r);
}
#define DPP_XOR1 0xB1   // quad_perm [1,0,3,2]
#define DPP_XOR2 0x4E   // quad_perm [2,3,0,1]

// One thread per (basin, mul). Block = 64 threads = 1 wave = 8 basins.
// Params + forcings streamed global->LDS via global_load_lds, depth-2 chunk
// pipeline with counted vmcnt (never 0 in main loop). Per-step mul-mean via
// DPP (xor1/xor2) + one shfl_xor(4); Q history in LDS; gamma routing conv
// fused (gammaln/th^aa denominator cancels under normalization).
__global__ __launch_bounds__(64) void prms_kernel(
    const float* __restrict__ P, const float* __restrict__ Ep,
    const float* __restrict__ Tair, const float* __restrict__ params,
    const float* __restrict__ rout_a, const float* __restrict__ rout_b,
    float* __restrict__ out)
{
  __shared__ __attribute__((aligned(16))) float sh_par[2][8 * BWORDS]; // 49408 B
  __shared__ __attribute__((aligned(16))) float sh_frc[2][3][64];      //  1536 B
  __shared__ float Qs[8][NT + 1];                                      // 11712 B

  const int lane = threadIdx.x;      // 0..63
  const int lb   = lane >> 3;        // local basin 0..7
  const int m    = lane & 7;         // mul index
  const int b0   = blockIdx.x * 8;   // first basin of this block (grid exact)
  const int b    = b0 + lb;

  // preload routing params early — latency hidden under the scan
  const float ra_v = rout_a[b];
  const float rb_v = rout_b[b];

  // ---- staging: 24x GLD16 (params) + 3x GLD4 (forcings) per chunk ----
  auto ISSUE = [&](int c, int buf) {
    #pragma unroll
    for (int q = 0; q < 8; ++q) {
      const char* gb = (const char*)(params + (size_t)(b0 + q) * (NT * PSTRIDE));
      #pragma unroll
      for (int j = 0; j < 3; ++j) {
        int off = c * (CH * PSTRIDE * 4) + j * 1024 + lane * 16;
        off = off > CLAMP16 ? CLAMP16 : off;   // tail clamp (dup reads, unused)
        GLD16(gb + off, &sh_par[buf][q * BWORDS + j * 256]);
      }
    }
    const int fl = lane >> 3, fs = lane & 7;   // lane i -> (basin fl, step fs)
    int foff = c * (CH * 4) + fs * 4;
    foff = foff > FCLAMP ? FCLAMP : foff;
    GLD4((const char*)(P    + (size_t)(b0 + fl) * NT) + foff, &sh_frc[buf][0][0]);
    GLD4((const char*)(Ep   + (size_t)(b0 + fl) * NT) + foff, &sh_frc[buf][1][0]);
    GLD4((const char*)(Tair + (size_t)(b0 + fl) * NT) + foff, &sh_frc[buf][2][0]);
  };

  float S1 = 0.5f, S2 = 0.5f, S3 = 0.5f, S4 = 0.5f, S5 = 0.5f;
  const int pbase = lb * BWORDS + m;   // per-thread param word base
  const int fbase = lb * 8;

  auto STEP = [&](int buf, int s, int t) {
    const float* par = &sh_par[buf][pbase + s * PSTRIDE];
    const float v0  = par[0];    // pr0  -> tt
    const float v1  = par[8];    // pr1  -> ddf
    const float v3  = par[24];   // pr3  -> Smax3
    const float v4  = par[32];   // pr4  -> p_lo
    const float v5  = par[40];   // pr5  -> p_hi
    const float v6  = par[48];   // pr6  -> p_exp
    const float i1  = par[64];   // pr8
    const float i2  = par[72] * 0.001f;  // pr9
    const float kb  = par[80];   // pr10
    const float Pt  = sh_frc[buf][0][fbase + s];
    const float Ept = sh_frc[buf][1][fbase + s];
    const float Tt  = sh_frc[buf][2][fbase + s];

    const float tt    = fmaf(v0, 8.0f, -3.0f);
    const float ddf   = v1 * 20.0f;
    const float Smax3 = fmaf(v3, 680.0f, 20.0f);
    const float p_lo  = fmaf(v4, 0.99f, 0.005f);
    const float p_hi  = fmaf(v5, 0.99f, 0.005f);
    const float p_exp = fmaf(v6, 4.0f, 1.0f);

    const float snow = (Tt <= tt) ? Pt : 0.0f;
    const float rain = Pt - snow;
    const float melt = fmaxf(fminf(ddf * (Tt - tt), S1), 0.0f);   // DT=1
    S1 = S1 + snow - melt;

    const float inter = rain * 0.95f;
    const float evap2 = fminf(S2, Ept);
    S2 = fmaxf(S2 + (rain - inter) - evap2, 0.0f);

    const float infil  = melt + inter;
    const float frac   = fmaxf(S3, 0.0f) * __builtin_amdgcn_rcpf(Smax3);
    const float satexc = (p_lo + (p_hi - p_lo) * frac) * infil;
    const float rem    = fmaxf(infil - satexc, 0.0f);
    // frac^p_exp: frac==0 -> log2=-inf -> exp2(-inf)=0 (matches 0**p, p>=1)
    const float rech   = rem * EXP2F(p_exp * LOG2F(frac));
    const float evap3  = fminf(frac * Ept, S3);
    S3 = S3 + rem - rech - evap3;

    const float S4c   = fmaxf(S4, 0.0f);
    const float iflow = fminf(S4c, fmaf(i2, S4c * S4c, i1 * S4c));
    S4 = S4 + rech - iflow;

    const float base = kb * S5;
    S5 = S5 + iflow - base;

    float q = satexc + base;
    // mean over the 8 muls: xor1/xor2 via DPP (VALU), xor4 via shfl
    q += dpp_xor<DPP_XOR1>(q);
    q += dpp_xor<DPP_XOR2>(q);
    q += __shfl_xor(q, 4);
    if (m == 0) Qs[lb][t] = q * 0.125f;
  };

  // ---- depth-2 pipeline over 46 chunks ----
  ISSUE(0, 0);
  ISSUE(1, 1);
  for (int c = 0; c < NFULL; ++c) {
    asm volatile("s_waitcnt vmcnt(27)" ::: "memory");  // chunk c resident (c+1 in flight)
    const int buf = c & 1;
    #pragma unroll
    for (int s = 0; s < CH; ++s) STEP(buf, s, c * CH + s);
    asm volatile("s_waitcnt lgkmcnt(0)" ::: "memory"); // reads of buf drained
    if (c + 2 < NCHUNK) ISSUE(c + 2, buf);
  }
  // tail chunk (c = 45): 5 valid steps
  asm volatile("s_waitcnt vmcnt(0)" ::: "memory");
  #pragma unroll
  for (int s = 0; s < 5; ++s) STEP(NFULL & 1, s, NFULL * CH + s);

  __syncthreads();

  // ---- fused gamma routing conv ----
  const float aa  = fmaxf(ra_v * 2.9f, 0.0f) + 0.1f;
  const float th  = fmaxf(rb_v * 6.5f, 0.0f) + 0.5f;
  const float am1 = aa - 1.0f;
  const float ith = -LOG2E / th;

  float w[LENF];
  float wsum = 0.0f;
  #pragma unroll
  for (int j = 0; j < LENF; ++j) {
    const float tj = (float)j + 0.5f;
    w[j] = EXP2F(fmaf(am1, LOG2F(tj), tj * ith));
    wsum += w[j];
  }
  const float inv = 1.0f / wsum;
  #pragma unroll
  for (int j = 0; j < LENF; ++j) w[j] *= inv;

  float* __restrict__ ob = out + (size_t)b * NT;
  for (int t = m; t < NT; t += NMUL) {
    float acc = 0.0f;
    #pragma unroll
    for (int j = 0; j < LENF; ++j) {
      const int idx = t - j;
      if (idx >= 0) acc += w[j] * Qs[lb][idx];
    }
    ob[t] = acc;
  }
}

extern "C" void kernel_launch(void* const* d_in, const int* in_sizes, int n_in,
                              void* d_out, int out_size, void* d_ws, size_t ws_size,
                              hipStream_t stream) {
  const float* P      = (const float*)d_in[0];
  const float* Ep     = (const float*)d_in[1];
  const float* Tair   = (const float*)d_in[2];
  const float* params = (const float*)d_in[3];
  const float* ra     = (const float*)d_in[4];
  const float* rb     = (const float*)d_in[5];
  float* out = (float*)d_out;

  prms_kernel<<<(NB * NMUL) / 64, 64, 0, stream>>>(P, Ep, Tair, params, ra, rb, out);
}

// Round 6
// 115.467 us; speedup vs baseline: 1.2453x; 1.0972x over previous
//
#include <hip/hip_runtime.h>

#define NB      2000
#define NT      365
#define LENF    15
#define PSTRIDE 96              // 12 params * 8 muls, floats per (b,t)
#define CH      8               // timesteps per chunk
#define NFULL   45              // full chunks (360 steps)
#define NCHUNK  46              // incl. 5-step tail
#define CHBYTES (CH * PSTRIDE * 4)              // 3072 B per chunk
#define BASIN_BYTES (NT * PSTRIDE * 4)          // 140160
#define CLAMP16     (BASIN_BYTES - 16)          // 140144

#define GLD16(g, l) __builtin_amdgcn_global_load_lds( \
    (const __attribute__((address_space(1))) void*)(g), \
    (__attribute__((address_space(3))) void*)(l), 16, 0, 0)
#define GLD4(g, l) __builtin_amdgcn_global_load_lds( \
    (const __attribute__((address_space(1))) void*)(g), \
    (__attribute__((address_space(3))) void*)(l), 4, 0, 0)

#define EXP2F(x) __builtin_amdgcn_exp2f(x)
#define LOG2F(x) __builtin_amdgcn_logf(x)
#define LOG2E    1.44269504088896f

// DPP cross-lane xor within quads — pure VALU, no LDS latency, no lgkmcnt.
// (Final xor-4 step uses __shfl_xor: DPP row_shr/row_shl shift, not xor —
// R5's row_shr:4 zeroed lane 0's partner via bound_ctrl and dropped muls 4-7.)
template <int CTRL>
__device__ __forceinline__ float dpp_mov(float x) {
  int xi = __float_as_int(x);
  int r  = __builtin_amdgcn_update_dpp(xi, xi, CTRL, 0xF, 0xF, true);
  return __int_as_float(r);
}
#define DPP_XOR1 0xB1   // quad_perm [1,0,3,2]
#define DPP_XOR2 0x4E   // quad_perm [2,3,0,1]

// ONE WAVE PER BASIN: 2000 blocks x 64 threads -> ~8 waves/CU (TLP hides
// latency; the 8-basins-per-wave layout had 1 wave/CU and both pipes <6% busy).
// Lanes 0-7 = the 8 muls; lanes 8-63 compute duplicates off broadcast LDS
// reads (VALU has 8x headroom). Params+forcings stream global->LDS via
// global_load_lds (4 VMEM/chunk), depth-2 pipeline, counted vmcnt.
// Mul-mean = 2 DPP + 1 shfl (off the S-state critical chain).
// Gamma routing conv fused (gammaln/th^aa denominator cancels under norm).
__global__ __launch_bounds__(64) void prms_kernel(
    const float* __restrict__ P, const float* __restrict__ Ep,
    const float* __restrict__ Tair, const float* __restrict__ params,
    const float* __restrict__ rout_a, const float* __restrict__ rout_b,
    float* __restrict__ out)
{
  __shared__ __attribute__((aligned(16))) float sh_par[2][CH * PSTRIDE]; // 6144 B
  __shared__ __attribute__((aligned(16))) float sh_frc[2][64];           //  512 B
  __shared__ float Qs[NT + 3];                                           // 1472 B

  const int lane = threadIdx.x;   // 0..63
  const int m    = lane & 7;      // mul index (lanes 8-63 duplicate)
  const int b    = blockIdx.x;    // basin

  // preload routing params early — latency hidden under the scan
  const float ra_v = rout_a[b];
  const float rb_v = rout_b[b];

  const char*  pb = (const char*)(params + (size_t)b * (NT * PSTRIDE));
  const float* Pb = P    + (size_t)b * NT;
  const float* Eb = Ep   + (size_t)b * NT;
  const float* Tb = Tair + (size_t)b * NT;

  // per-lane forcing source: lanes 0-7 -> P, 8-15 -> Ep, 16-23 -> Tair,
  // 24-63 duplicate Tair (land in LDS words 24-63, never read)
  const int grp = lane >> 3;
  const float* fsrc = (grp == 0) ? Pb : (grp == 1) ? Eb : Tb;
  const int    fs   = lane & 7;

  // ---- staging: 3x GLD16 (params, 3072 B contiguous) + 1x GLD4 (forcings) ----
  auto ISSUE = [&](int c, int buf) {
    #pragma unroll
    for (int j = 0; j < 3; ++j) {
      int off = c * CHBYTES + j * 1024 + lane * 16;
      off = off > CLAMP16 ? CLAMP16 : off;   // tail clamp (dup reads, unused)
      GLD16(pb + off, &sh_par[buf][j * 256]);
    }
    int ft = c * CH + fs;
    ft = ft > NT - 1 ? NT - 1 : ft;
    GLD4(fsrc + ft, &sh_frc[buf][0]);
  };

  float S1 = 0.5f, S2 = 0.5f, S3 = 0.5f, S4 = 0.5f, S5 = 0.5f;

  auto STEP = [&](int buf, int s, int t) {
    const float* par = &sh_par[buf][m + s * PSTRIDE];
    const float v0  = par[0];            // pr0  -> tt
    const float v1  = par[8];            // pr1  -> ddf
    const float v3  = par[24];           // pr3  -> Smax3
    const float v4  = par[32];           // pr4  -> p_lo
    const float v5  = par[40];           // pr5  -> p_hi
    const float v6  = par[48];           // pr6  -> p_exp
    const float i1  = par[64];           // pr8
    const float i2  = par[72] * 0.001f;  // pr9
    const float kb  = par[80];           // pr10
    const float Pt  = sh_frc[buf][s];        // broadcast reads
    const float Ept = sh_frc[buf][8 + s];
    const float Tt  = sh_frc[buf][16 + s];

    const float tt    = fmaf(v0, 8.0f, -3.0f);
    const float ddf   = v1 * 20.0f;
    const float Smax3 = fmaf(v3, 680.0f, 20.0f);
    const float p_lo  = fmaf(v4, 0.99f, 0.005f);
    const float p_hi  = fmaf(v5, 0.99f, 0.005f);
    const float p_exp = fmaf(v6, 4.0f, 1.0f);

    const float snow = (Tt <= tt) ? Pt : 0.0f;
    const float rain = Pt - snow;
    const float melt = fmaxf(fminf(ddf * (Tt - tt), S1), 0.0f);   // DT=1
    S1 = S1 + snow - melt;

    const float inter = rain * 0.95f;
    const float evap2 = fminf(S2, Ept);
    S2 = fmaxf(S2 + (rain - inter) - evap2, 0.0f);

    const float infil  = melt + inter;
    const float frac   = fmaxf(S3, 0.0f) * __builtin_amdgcn_rcpf(Smax3);
    const float satexc = (p_lo + (p_hi - p_lo) * frac) * infil;
    const float rem    = fmaxf(infil - satexc, 0.0f);
    // frac^p_exp: frac==0 -> log2=-inf -> exp2(-inf)=0 (matches 0**p, p>=1)
    const float rech   = rem * EXP2F(p_exp * LOG2F(frac));
    const float evap3  = fminf(frac * Ept, S3);
    S3 = S3 + rem - rech - evap3;

    const float S4c   = fmaxf(S4, 0.0f);
    const float iflow = fminf(S4c, fmaf(i2, S4c * S4c, i1 * S4c));
    S4 = S4 + rech - iflow;

    const float base = kb * S5;
    S5 = S5 + iflow - base;

    float q = satexc + base;
    // sum over the 8 muls: quad sums via DPP xor, octet via shfl_xor(4)
    q += dpp_mov<DPP_XOR1>(q);
    q += dpp_mov<DPP_XOR2>(q);
    q += __shfl_xor(q, 4);
    if (lane == 0) Qs[t] = q * 0.125f;
  };

  // ---- depth-2 pipeline over 46 chunks (4 VMEM ops per chunk) ----
  ISSUE(0, 0);
  ISSUE(1, 1);
  for (int c = 0; c < NFULL; ++c) {
    asm volatile("s_waitcnt vmcnt(4)" ::: "memory");   // chunk c resident (c+1 in flight)
    const int buf = c & 1;
    #pragma unroll
    for (int s = 0; s < CH; ++s) STEP(buf, s, c * CH + s);
    asm volatile("s_waitcnt lgkmcnt(0)" ::: "memory"); // reads of buf drained
    if (c + 2 < NCHUNK) ISSUE(c + 2, buf);
  }
  // tail chunk (c = 45): 5 valid steps
  asm volatile("s_waitcnt vmcnt(0)" ::: "memory");
  #pragma unroll
  for (int s = 0; s < 5; ++s) STEP(NFULL & 1, s, NFULL * CH + s);

  __syncthreads();

  // ---- fused gamma routing conv (all 64 lanes) ----
  const float aa  = fmaxf(ra_v * 2.9f, 0.0f) + 0.1f;
  const float th  = fmaxf(rb_v * 6.5f, 0.0f) + 0.5f;
  const float am1 = aa - 1.0f;
  const float ith = -LOG2E / th;

  float w[LENF];
  float wsum = 0.0f;
  #pragma unroll
  for (int j = 0; j < LENF; ++j) {
    const float tj = (float)j + 0.5f;
    w[j] = EXP2F(fmaf(am1, LOG2F(tj), tj * ith));
    wsum += w[j];
  }
  const float inv = 1.0f / wsum;
  #pragma unroll
  for (int j = 0; j < LENF; ++j) w[j] *= inv;

  float* __restrict__ ob = out + (size_t)b * NT;
  #pragma unroll
  for (int k = 0; k < 6; ++k) {
    const int t = lane + k * 64;
    if (t < NT) {
      float acc = 0.0f;
      #pragma unroll
      for (int j = 0; j < LENF; ++j) {
        const int idx = t - j;
        if (idx >= 0) acc += w[j] * Qs[idx];
      }
      ob[t] = acc;
    }
  }
}

extern "C" void kernel_launch(void* const* d_in, const int* in_sizes, int n_in,
                              void* d_out, int out_size, void* d_ws, size_t ws_size,
                              hipStream_t stream) {
  const float* P      = (const float*)d_in[0];
  const float* Ep     = (const float*)d_in[1];
  const float* Tair   = (const float*)d_in[2];
  const float* params = (const float*)d_in[3];
  const float* ra     = (const float*)d_in[4];
  const float* rb     = (const float*)d_in[5];
  float* out = (float*)d_out;

  prms_kernel<<<NB, 64, 0, stream>>>(P, Ep, Tair, params, ra, rb, out);
}

// Round 7
// 87.952 us; speedup vs baseline: 1.6349x; 1.3128x over previous
//
#include <hip/hip_runtime.h>

#define NB      2000
#define NT      365
#define LENF    15
#define PSTRIDE 96              // 12 params * 8 muls, floats per (b,t)
#define CH      16              // timesteps per chunk
#define NFULL   22              // full chunks (352 steps)
#define NCHUNK  23              // incl. 13-step tail
#define CHBYTES (CH * PSTRIDE * 4)              // 6144 B per chunk per basin
#define BASIN_BYTES (NT * PSTRIDE * 4)          // 140160
#define CLAMP16     (BASIN_BYTES - 16)          // 140144
#define PARW    1544            // LDS words per basin param block (1536 + 8 pad; 1544%32==8)
#define FRCW    72              // LDS words per basin forcing block (48 data + pad; 72%32==8)

#define GLD16(g, l) __builtin_amdgcn_global_load_lds( \
    (const __attribute__((address_space(1))) void*)(g), \
    (__attribute__((address_space(3))) void*)(l), 16, 0, 0)
#define GLD4(g, l) __builtin_amdgcn_global_load_lds( \
    (const __attribute__((address_space(1))) void*)(g), \
    (__attribute__((address_space(3))) void*)(l), 4, 0, 0)

#define EXP2F(x) __builtin_amdgcn_exp2f(x)
#define LOG2F(x) __builtin_amdgcn_logf(x)
#define LOG2E    1.44269504088896f

// DPP cross-lane ops — pure VALU, no LDS pipe, no lgkmcnt.
template <int CTRL>
__device__ __forceinline__ float dpp_mov(float x) {
  int xi = __float_as_int(x);
  int r  = __builtin_amdgcn_update_dpp(xi, xi, CTRL, 0xF, 0xF, true);
  return __int_as_float(r);
}
#define DPP_XOR1   0xB1    // quad_perm [1,0,3,2]
#define DPP_XOR2   0x4E    // quad_perm [2,3,0,1]
#define DPP_HMIRR  0x141   // row_half_mirror: i <-> 7-i within each 8-lane half
// octet sum = xor1 + xor2 (quad sums) + half-mirror (combines the two quads)

// TWO BASINS PER WAVE, x4 lane duplication: lane = d*16 + bsel*8 + m.
// 1000 blocks x 64 -> ~4 waves/CU (1/SIMD). Halves per-CU LDS+VALU issue
// vs the 1-basin/wave layout (which was LDS-pipe-bound at ~13 DS/step:
// 8 waves x 13 x 365 x 5.8cy ~= 92us). Mul-mean is now 3 DPP ops (no shfl).
// Params+forcings stream global->LDS via global_load_lds, CH=16 chunks,
// depth-2 counted-vmcnt pipeline. Gamma conv fused (gammaln cancels).
__global__ __launch_bounds__(64) void prms_kernel(
    const float* __restrict__ P, const float* __restrict__ Ep,
    const float* __restrict__ Tair, const float* __restrict__ params,
    const float* __restrict__ rout_a, const float* __restrict__ rout_b,
    float* __restrict__ out)
{
  __shared__ __attribute__((aligned(16))) float sh_par[2][2 * PARW];  // 24704 B
  __shared__ __attribute__((aligned(16))) float sh_frc[2][2][FRCW];   //  1152 B
  __shared__ float Qs[2][NT + 3];                                     //  2944 B

  const int lane = threadIdx.x;        // 0..63
  const int m    = lane & 7;           // mul index
  const int bsel = (lane >> 3) & 1;    // which of the wave's 2 basins
  const int b0   = blockIdx.x * 2;     // first basin of this block

  // preload routing params early — latency hidden under the scan
  const float ra0 = rout_a[b0],     rb0 = rout_b[b0];
  const float ra1 = rout_a[b0 + 1], rb1 = rout_b[b0 + 1];

  const char* pbg[2] = {
    (const char*)(params + (size_t)b0 * (NT * PSTRIDE)),
    (const char*)(params + (size_t)(b0 + 1) * (NT * PSTRIDE)) };

  // forcing source for the GLD4s: lane -> (arr = lane>>4 clamped, s = lane&15)
  const int farr = (lane >> 4) > 2 ? 2 : (lane >> 4);
  const int fs   = lane & 15;
  const float* fsrcs[2][3] = {
    { P + (size_t)b0 * NT,       Ep + (size_t)b0 * NT,       Tair + (size_t)b0 * NT },
    { P + (size_t)(b0 + 1) * NT, Ep + (size_t)(b0 + 1) * NT, Tair + (size_t)(b0 + 1) * NT } };

  // ---- staging: 12x GLD16 (params) + 2x GLD4 (forcings) per chunk ----
  auto ISSUE = [&](int c, int buf) {
    #pragma unroll
    for (int bs = 0; bs < 2; ++bs) {
      #pragma unroll
      for (int j = 0; j < 6; ++j) {
        int off = c * CHBYTES + j * 1024 + lane * 16;
        off = off > CLAMP16 ? CLAMP16 : off;   // tail clamp (dups land in pad)
        GLD16(pbg[bs] + off, &sh_par[buf][bs * PARW + j * 256]);
      }
    }
    #pragma unroll
    for (int bs = 0; bs < 2; ++bs) {
      int ft = c * CH + fs;
      ft = ft > NT - 1 ? NT - 1 : ft;
      GLD4(fsrcs[bs][farr] + ft, &sh_frc[buf][bs][0]);
    }
  };

  float S1 = 0.5f, S2 = 0.5f, S3 = 0.5f, S4 = 0.5f, S5 = 0.5f;
  const int pbase = bsel * PARW + m;    // thread-const param word base
  const int fbb   = bsel * FRCW;        // thread-const forcing base (within [2][FRCW])

  auto STEP = [&](int buf, int s, int t) {
    const float* par = &sh_par[buf][pbase + s * PSTRIDE];
    const float* f   = &sh_frc[buf][0][fbb];
    const float v0  = par[0];            // pr0  -> tt
    const float v1  = par[8];            // pr1  -> ddf
    const float v3  = par[24];           // pr3  -> Smax3
    const float v4  = par[32];           // pr4  -> p_lo
    const float v5  = par[40];           // pr5  -> p_hi
    const float v6  = par[48];           // pr6  -> p_exp
    const float i1  = par[64];           // pr8
    const float i2  = par[72] * 0.001f;  // pr9
    const float kb  = par[80];           // pr10
    const float Pt  = f[s];              // arr 0
    const float Ept = f[16 + s];         // arr 1
    const float Tt  = f[32 + s];         // arr 2

    const float tt    = fmaf(v0, 8.0f, -3.0f);
    const float ddf   = v1 * 20.0f;
    const float Smax3 = fmaf(v3, 680.0f, 20.0f);
    const float p_lo  = fmaf(v4, 0.99f, 0.005f);
    const float p_hi  = fmaf(v5, 0.99f, 0.005f);
    const float p_exp = fmaf(v6, 4.0f, 1.0f);

    const float snow = (Tt <= tt) ? Pt : 0.0f;
    const float rain = Pt - snow;
    const float melt = fmaxf(fminf(ddf * (Tt - tt), S1), 0.0f);   // DT=1
    S1 = S1 + snow - melt;

    const float inter = rain * 0.95f;
    const float evap2 = fminf(S2, Ept);
    S2 = fmaxf(S2 + (rain - inter) - evap2, 0.0f);

    const float infil  = melt + inter;
    const float frac   = fmaxf(S3, 0.0f) * __builtin_amdgcn_rcpf(Smax3);
    const float satexc = (p_lo + (p_hi - p_lo) * frac) * infil;
    const float rem    = fmaxf(infil - satexc, 0.0f);
    // frac^p_exp: frac==0 -> log2=-inf -> exp2(-inf)=0 (matches 0**p, p>=1)
    const float rech   = rem * EXP2F(p_exp * LOG2F(frac));
    const float evap3  = fminf(frac * Ept, S3);
    S3 = S3 + rem - rech - evap3;

    const float S4c   = fmaxf(S4, 0.0f);
    const float iflow = fminf(S4c, fmaf(i2, S4c * S4c, i1 * S4c));
    S4 = S4 + rech - iflow;

    const float base = kb * S5;
    S5 = S5 + iflow - base;

    float q = satexc + base;
    // sum over the 8 muls, all-VALU: quad sums via two quad_perm xors,
    // then row_half_mirror pairs each lane with the opposite quad's sum.
    q += dpp_mov<DPP_XOR1>(q);
    q += dpp_mov<DPP_XOR2>(q);
    q += dpp_mov<DPP_HMIRR>(q);
    if ((lane & 55) == 0)                // lanes 0 (basin0) and 8 (basin1)
      Qs[bsel][t] = q * 0.125f;
  };

  // ---- depth-2 pipeline over 23 chunks (14 VMEM ops per chunk) ----
  ISSUE(0, 0);
  ISSUE(1, 1);
  for (int c = 0; c < NFULL; ++c) {
    asm volatile("s_waitcnt vmcnt(14)" ::: "memory");   // chunk c resident
    const int buf = c & 1;
    #pragma unroll
    for (int s = 0; s < CH; ++s) STEP(buf, s, c * CH + s);
    asm volatile("s_waitcnt lgkmcnt(0)" ::: "memory");  // reads of buf drained
    if (c + 2 < NCHUNK) ISSUE(c + 2, buf);
  }
  // tail chunk (c = 22): 13 valid steps, buf = 0
  asm volatile("s_waitcnt vmcnt(0)" ::: "memory");
  #pragma unroll
  for (int s = 0; s < 13; ++s) STEP(0, s, NFULL * CH + s);

  __syncthreads();

  // ---- fused gamma routing conv, per basin (all 64 lanes) ----
  #pragma unroll
  for (int bs = 0; bs < 2; ++bs) {
    const float ra_v = bs ? ra1 : ra0;
    const float rb_v = bs ? rb1 : rb0;
    const float aa  = fmaxf(ra_v * 2.9f, 0.0f) + 0.1f;
    const float th  = fmaxf(rb_v * 6.5f, 0.0f) + 0.5f;
    const float am1 = aa - 1.0f;
    const float ith = -LOG2E / th;

    float w[LENF];
    float wsum = 0.0f;
    #pragma unroll
    for (int j = 0; j < LENF; ++j) {
      const float tj = (float)j + 0.5f;
      w[j] = EXP2F(fmaf(am1, LOG2F(tj), tj * ith));
      wsum += w[j];
    }
    const float inv = 1.0f / wsum;
    #pragma unroll
    for (int j = 0; j < LENF; ++j) w[j] *= inv;

    float* __restrict__ ob = out + (size_t)(b0 + bs) * NT;
    #pragma unroll
    for (int k = 0; k < 6; ++k) {
      const int t = lane + k * 64;
      if (t < NT) {
        float acc = 0.0f;
        #pragma unroll
        for (int j = 0; j < LENF; ++j) {
          const int idx = t - j;
          if (idx >= 0) acc += w[j] * Qs[bs][idx];
        }
        ob[t] = acc;
      }
    }
  }
}

extern "C" void kernel_launch(void* const* d_in, const int* in_sizes, int n_in,
                              void* d_out, int out_size, void* d_ws, size_t ws_size,
                              hipStream_t stream) {
  const float* P      = (const float*)d_in[0];
  const float* Ep     = (const float*)d_in[1];
  const float* Tair   = (const float*)d_in[2];
  const float* params = (const float*)d_in[3];
  const float* ra     = (const float*)d_in[4];
  const float* rb     = (const float*)d_in[5];
  float* out = (float*)d_out;

  prms_kernel<<<NB / 2, 64, 0, stream>>>(P, Ep, Tair, params, ra, rb, out);
}

// Round 8
// 80.735 us; speedup vs baseline: 1.7811x; 1.0894x over previous
//
#include <hip/hip_runtime.h>

#define NB      2000
#define NT      365
#define LENF    15
#define PSTRIDE 96              // 12 params * 8 muls, floats per (b,t)
#define CH      16              // timesteps per chunk
#define NFULL   22              // full chunks (352 steps)
#define NCHUNK  23              // incl. 13-step tail
#define CHBYTES (CH * PSTRIDE * 4)              // 6144 B per chunk per basin
#define BASIN_BYTES (NT * PSTRIDE * 4)          // 140160
#define CLAMP16     (BASIN_BYTES - 16)          // 140144
#define PARW    1544            // LDS words per basin param block (1536 + 8 pad; 1544%32==8)
#define FRCW    72              // LDS words per basin forcing block (48 data + pad; 72%32==8)

#define GLD16(g, l) __builtin_amdgcn_global_load_lds( \
    (const __attribute__((address_space(1))) void*)(g), \
    (__attribute__((address_space(3))) void*)(l), 16, 0, 0)
#define GLD4(g, l) __builtin_amdgcn_global_load_lds( \
    (const __attribute__((address_space(1))) void*)(g), \
    (__attribute__((address_space(3))) void*)(l), 4, 0, 0)

#define EXP2F(x) __builtin_amdgcn_exp2f(x)
#define LOG2F(x) __builtin_amdgcn_logf(x)
#define LOG2E    1.44269504088896f

// DPP cross-lane ops — pure VALU, no LDS pipe, no lgkmcnt.
template <int CTRL>
__device__ __forceinline__ float dpp_mov(float x) {
  int xi = __float_as_int(x);
  int r  = __builtin_amdgcn_update_dpp(xi, xi, CTRL, 0xF, 0xF, true);
  return __int_as_float(r);
}
#define DPP_XOR1   0xB1    // quad_perm [1,0,3,2]
#define DPP_XOR2   0x4E    // quad_perm [2,3,0,1]
#define DPP_HMIRR  0x141   // row_half_mirror: i <-> 7-i within each 8-lane half

// TWO BASINS PER WAVE (lane = d*16 + bsel*8 + m), 1000 blocks -> 3.9 waves/CU.
// R7 ran 88us vs a 41us LDS-issue floor: with ~1 wave/SIMD the per-step
// load->wait->compute pattern exposes ~120cy LDS latency every step.
// This version register-batches 4 steps (rA/rB double-buffer, all indices
// compile-time) and interleaves LOADB(next) with STEP4(current) so ds_read
// latency hides under the previous batch's VALU chain (ILP, since TLP is absent).
__global__ __launch_bounds__(64) void prms_kernel(
    const float* __restrict__ P, const float* __restrict__ Ep,
    const float* __restrict__ Tair, const float* __restrict__ params,
    const float* __restrict__ rout_a, const float* __restrict__ rout_b,
    float* __restrict__ out)
{
  __shared__ __attribute__((aligned(16))) float sh_par[2][2 * PARW];  // 24704 B
  __shared__ __attribute__((aligned(16))) float sh_frc[2][2][FRCW];   //  1152 B
  __shared__ float Qs[2][NT + 3];                                     //  2944 B

  const int lane = threadIdx.x;        // 0..63
  const int m    = lane & 7;           // mul index
  const int bsel = (lane >> 3) & 1;    // which of the wave's 2 basins
  const int b0   = blockIdx.x * 2;     // first basin of this block

  // preload routing params early — latency hidden under the scan
  const float ra0 = rout_a[b0],     rb0 = rout_b[b0];
  const float ra1 = rout_a[b0 + 1], rb1 = rout_b[b0 + 1];

  const char* pbg[2] = {
    (const char*)(params + (size_t)b0 * (NT * PSTRIDE)),
    (const char*)(params + (size_t)(b0 + 1) * (NT * PSTRIDE)) };

  // forcing source for the GLD4s: lane -> (arr = lane>>4 clamped, s = lane&15)
  const int farr = (lane >> 4) > 2 ? 2 : (lane >> 4);
  const int fs   = lane & 15;
  const float* fsrcs[2][3] = {
    { P + (size_t)b0 * NT,       Ep + (size_t)b0 * NT,       Tair + (size_t)b0 * NT },
    { P + (size_t)(b0 + 1) * NT, Ep + (size_t)(b0 + 1) * NT, Tair + (size_t)(b0 + 1) * NT } };

  // ---- staging: 12x GLD16 (params) + 2x GLD4 (forcings) per chunk ----
  auto ISSUE = [&](int c, int buf) {
    #pragma unroll
    for (int bs = 0; bs < 2; ++bs) {
      #pragma unroll
      for (int j = 0; j < 6; ++j) {
        int off = c * CHBYTES + j * 1024 + lane * 16;
        off = off > CLAMP16 ? CLAMP16 : off;   // tail clamp (dups land in pad)
        GLD16(pbg[bs] + off, &sh_par[buf][bs * PARW + j * 256]);
      }
    }
    #pragma unroll
    for (int bs = 0; bs < 2; ++bs) {
      int ft = c * CH + fs;
      ft = ft > NT - 1 ? NT - 1 : ft;
      GLD4(fsrcs[bs][farr] + ft, &sh_frc[buf][bs][0]);
    }
  };

  float S1 = 0.5f, S2 = 0.5f, S3 = 0.5f, S4 = 0.5f, S5 = 0.5f;
  const int pbase = bsel * PARW + m;    // thread-const param word base
  const int fbb   = bsel * FRCW;        // thread-const forcing base

  // ---- batched LDS->register loads: 4 steps x 12 values, static indices ----
  auto LOADB = [&](int buf, int s0, float r[4][12]) {
    #pragma unroll
    for (int k = 0; k < 4; ++k) {
      const float* par = &sh_par[buf][pbase + (s0 + k) * PSTRIDE];
      r[k][0] = par[0];   r[k][1] = par[8];   r[k][2] = par[24];
      r[k][3] = par[32];  r[k][4] = par[40];  r[k][5] = par[48];
      r[k][6] = par[64];  r[k][7] = par[72];  r[k][8] = par[80];
      const float* f = &sh_frc[buf][0][fbb];
      r[k][9]  = f[s0 + k];
      r[k][10] = f[16 + s0 + k];
      r[k][11] = f[32 + s0 + k];
    }
  };

  // ---- one step of the hydrology scan from a 12-value register vector ----
  auto STEPD = [&](const float* d, int t) {
    const float tt    = fmaf(d[0], 8.0f, -3.0f);
    const float ddf   = d[1] * 20.0f;
    const float Smax3 = fmaf(d[2], 680.0f, 20.0f);
    const float p_lo  = fmaf(d[3], 0.99f, 0.005f);
    const float p_hi  = fmaf(d[4], 0.99f, 0.005f);
    const float p_exp = fmaf(d[5], 4.0f, 1.0f);
    const float i1    = d[6];
    const float i2    = d[7] * 0.001f;
    const float kb    = d[8];
    const float Pt    = d[9];
    const float Ept   = d[10];
    const float Tt    = d[11];

    const float snow = (Tt <= tt) ? Pt : 0.0f;
    const float rain = Pt - snow;
    const float melt = fmaxf(fminf(ddf * (Tt - tt), S1), 0.0f);   // DT=1
    S1 = S1 + snow - melt;

    const float inter = rain * 0.95f;
    const float evap2 = fminf(S2, Ept);
    S2 = fmaxf(S2 + (rain - inter) - evap2, 0.0f);

    const float infil  = melt + inter;
    const float frac   = fmaxf(S3, 0.0f) * __builtin_amdgcn_rcpf(Smax3);
    const float satexc = (p_lo + (p_hi - p_lo) * frac) * infil;
    const float rem    = fmaxf(infil - satexc, 0.0f);
    // frac^p_exp: frac==0 -> log2=-inf -> exp2(-inf)=0 (matches 0**p, p>=1)
    const float rech   = rem * EXP2F(p_exp * LOG2F(frac));
    const float evap3  = fminf(frac * Ept, S3);
    S3 = S3 + rem - rech - evap3;

    const float S4c   = fmaxf(S4, 0.0f);
    const float iflow = fminf(S4c, fmaf(i2, S4c * S4c, i1 * S4c));
    S4 = S4 + rech - iflow;

    const float base = kb * S5;
    S5 = S5 + iflow - base;

    float q = satexc + base;
    q += dpp_mov<DPP_XOR1>(q);
    q += dpp_mov<DPP_XOR2>(q);
    q += dpp_mov<DPP_HMIRR>(q);
    if ((lane & 55) == 0)                // lanes 0 (basin0) and 8 (basin1)
      Qs[bsel][t] = q * 0.125f;
  };

  float rA[4][12], rB[4][12];
  auto STEP4 = [&](float r[4][12], int tb) {
    #pragma unroll
    for (int k = 0; k < 4; ++k) STEPD(r[k], tb + k);
  };

  // ---- depth-2 chunk pipeline, 4-step register double-buffer inside ----
  ISSUE(0, 0);
  ISSUE(1, 1);
  for (int c = 0; c < NFULL; ++c) {
    asm volatile("s_waitcnt vmcnt(14)" ::: "memory");   // chunk c resident
    const int buf = c & 1;
    const int t0  = c * CH;
    LOADB(buf, 0,  rA);
    LOADB(buf, 4,  rB);  STEP4(rA, t0);
    LOADB(buf, 8,  rA);  STEP4(rB, t0 + 4);
    LOADB(buf, 12, rB);  STEP4(rA, t0 + 8);
    STEP4(rB, t0 + 12);
    asm volatile("s_waitcnt lgkmcnt(0)" ::: "memory");  // reads of buf drained
    if (c + 2 < NCHUNK) ISSUE(c + 2, buf);
  }
  // tail chunk (c = 22): 13 valid steps, buf = 0
  asm volatile("s_waitcnt vmcnt(0)" ::: "memory");
  {
    const int t0 = NFULL * CH;           // 352
    LOADB(0, 0, rA);
    LOADB(0, 4, rB);  STEP4(rA, t0);
    LOADB(0, 8, rA);  STEP4(rB, t0 + 4);
    STEP4(rA, t0 + 8);                   // steps 360..363
    // final step t=364 (s=12)
    float d12[12];
    {
      const float* par = &sh_par[0][pbase + 12 * PSTRIDE];
      d12[0] = par[0];  d12[1] = par[8];  d12[2] = par[24];
      d12[3] = par[32]; d12[4] = par[40]; d12[5] = par[48];
      d12[6] = par[64]; d12[7] = par[72]; d12[8] = par[80];
      const float* f = &sh_frc[0][0][fbb];
      d12[9] = f[12]; d12[10] = f[28]; d12[11] = f[44];
    }
    STEPD(d12, t0 + 12);
  }

  __syncthreads();

  // ---- fused gamma routing conv, per basin (all 64 lanes) ----
  #pragma unroll
  for (int bs = 0; bs < 2; ++bs) {
    const float ra_v = bs ? ra1 : ra0;
    const float rb_v = bs ? rb1 : rb0;
    const float aa  = fmaxf(ra_v * 2.9f, 0.0f) + 0.1f;
    const float th  = fmaxf(rb_v * 6.5f, 0.0f) + 0.5f;
    const float am1 = aa - 1.0f;
    const float ith = -LOG2E / th;

    float w[LENF];
    float wsum = 0.0f;
    #pragma unroll
    for (int j = 0; j < LENF; ++j) {
      const float tj = (float)j + 0.5f;
      w[j] = EXP2F(fmaf(am1, LOG2F(tj), tj * ith));
      wsum += w[j];
    }
    const float inv = 1.0f / wsum;
    #pragma unroll
    for (int j = 0; j < LENF; ++j) w[j] *= inv;

    float* __restrict__ ob = out + (size_t)(b0 + bs) * NT;
    #pragma unroll
    for (int k = 0; k < 6; ++k) {
      const int t = lane + k * 64;
      if (t < NT) {
        float acc = 0.0f;
        #pragma unroll
        for (int j = 0; j < LENF; ++j) {
          const int idx = t - j;
          if (idx >= 0) acc += w[j] * Qs[bs][idx];
        }
        ob[t] = acc;
      }
    }
  }
}

extern "C" void kernel_launch(void* const* d_in, const int* in_sizes, int n_in,
                              void* d_out, int out_size, void* d_ws, size_t ws_size,
                              hipStream_t stream) {
  const float* P      = (const float*)d_in[0];
  const float* Ep     = (const float*)d_in[1];
  const float* Tair   = (const float*)d_in[2];
  const float* params = (const float*)d_in[3];
  const float* ra     = (const float*)d_in[4];
  const float* rb     = (const float*)d_in[5];
  float* out = (float*)d_out;

  prms_kernel<<<NB / 2, 64, 0, stream>>>(P, Ep, Tair, params, ra, rb, out);
}